// Round 3
// baseline (563.622 us; speedup 1.0000x reference)
//
#include <hip/hip_runtime.h>
#include <math.h>

#define B_ 32
#define S_ 2048
#define D_ 1024
#define H_ 16
#define HD_ 64
#define MODES_ 16
#define EPS_ 1e-5f

#define CHUNK_ 128
#define SUB_ 8
#define NSUB_ (CHUNK_ / SUB_)   // 16
#define NCH_ (S_ / CHUNK_)      // 16 chunks

// workspace float offsets
#define OFF_Q     0                    // B*D = 32768
#define OFF_QK    32768                // B*H*D = 524288
#define OFF_CK    557056               // B*H = 512
#define OFF_ML    557568               // 2 * NCH*B*H = 2*8192
#define ML_L_OFF  8192
#define OFF_PART  573952               // NCH*B*H*D = 8388608
#define OFF_XCTX  8962560              // B*H*D = 524288
#define OFF_Z3    9486848              // B*D = 32768

// ---------------- q[b,n] = z_prev[b,:].Wq[n,:] + bq[n] ; ck[b,h] = q.bk ----------------
__global__ void k_q(const float* __restrict__ zprev, const float* __restrict__ ipw,
                    const float* __restrict__ ipb, float* __restrict__ q_out,
                    float* __restrict__ ck_out) {
    int b = blockIdx.x >> 2, nc = blockIdx.x & 3;
    __shared__ float zr[D_];
    int t = threadIdx.x;
    for (int i = t; i < D_; i += 256) zr[i] = zprev[(size_t)b * D_ + i];
    __syncthreads();
    int n = nc * 256 + t;
    const float4* wr = (const float4*)(ipw + (size_t)n * D_);
    float acc = 0.f;
    for (int k = 0; k < D_ / 4; ++k) {
        float4 wv = wr[k];
        float4 zv = *(const float4*)&zr[4 * k];
        acc = fmaf(zv.x, wv.x, acc); acc = fmaf(zv.y, wv.y, acc);
        acc = fmaf(zv.z, wv.z, acc); acc = fmaf(zv.w, wv.w, acc);
    }
    float qv = acc + ipb[n];
    q_out[(size_t)b * D_ + n] = qv;
    // ck: head h = n>>6, wave-aligned
    float cv = qv * ipb[D_ + n];
#pragma unroll
    for (int o = 32; o > 0; o >>= 1) cv += __shfl_xor(cv, o);
    if ((t & 63) == 0) ck_out[b * H_ + (n >> 6)] = cv;
}

// ---------------- qk[b,h,n] = sum_i q[b,h*64+i] * Wk[h*64+i, n] ----------------
__global__ void k_qkc(const float* __restrict__ ipw, const float* __restrict__ q_in,
                      float* __restrict__ qk_out) {
    int bid = blockIdx.x;
    int bc = bid & 3, nc = (bid >> 2) & 3, h = bid >> 4;
    int t = threadIdx.x;
    __shared__ float4 tile4[HD_ * 64];   // 64 rows x 256 cols = 64KB
    __shared__ float qall[8 * HD_];
    const float4* wk4 = (const float4*)(ipw + (size_t)D_ * D_);
#pragma unroll
    for (int j = 0; j < 16; ++j) {
        int lin4 = j * 256 + t;
        int i = lin4 >> 6, n4 = lin4 & 63;
        tile4[lin4] = wk4[(size_t)(h * HD_ + i) * 256 + nc * 64 + n4];
    }
#pragma unroll
    for (int j = 0; j < 2; ++j) {
        int idx = j * 256 + t;
        int bb = idx >> 6, i = idx & 63;
        qall[idx] = q_in[(size_t)(bc * 8 + bb) * D_ + h * HD_ + i];
    }
    __syncthreads();
    const float* tile = (const float*)tile4;
#pragma unroll
    for (int bb = 0; bb < 8; ++bb) {
        float acc = 0.f;
#pragma unroll
        for (int i = 0; i < HD_; ++i) acc = fmaf(qall[bb * HD_ + i], tile[i * 256 + t], acc);
        int b = bc * 8 + bb;
        qk_out[(size_t)(b * H_ + h) * D_ + nc * 256 + t] = acc;
    }
}

// ---------------- fused attention pass: online softmax partials over x_feat (single read) ----
__global__ __launch_bounds__(256, 2) void k_attn(const float* __restrict__ xfeat,
        const float* __restrict__ qk, const float* __restrict__ ck,
        float* __restrict__ part, float* __restrict__ ml) {
    int bid = blockIdx.x;
    int b = bid >> 4, c = bid & 15;
    int t = threadIdx.x, w = t >> 6, l = t & 63;
    __shared__ float xs[SUB_ * D_];      // 32KB
    __shared__ float scs[4][SUB_ * 4];   // per-wave scores
    float4 qkr[4][4];
    float ckr[4];
#pragma unroll
    for (int j = 0; j < 4; ++j) {
        int h = w * 4 + j;
        ckr[j] = ck[b * H_ + h];
#pragma unroll
        for (int k2 = 0; k2 < 4; ++k2)
            qkr[j][k2] = *(const float4*)(qk + (size_t)(b * H_ + h) * D_ + k2 * 256 + 4 * l);
    }
    float4 acc[4][4];
#pragma unroll
    for (int j = 0; j < 4; ++j)
#pragma unroll
        for (int k2 = 0; k2 < 4; ++k2) acc[j][k2] = make_float4(0.f, 0.f, 0.f, 0.f);
    float mreg[4] = {-1e30f, -1e30f, -1e30f, -1e30f};
    float lreg[4] = {0.f, 0.f, 0.f, 0.f};
    const float4* xbase = (const float4*)(xfeat + ((size_t)b * S_ + c * CHUNK_) * D_);
    for (int i = 0; i < NSUB_; ++i) {
        __syncthreads();
        const float4* src = xbase + (size_t)i * (SUB_ * D_ / 4);
        float4 st[8];
#pragma unroll
        for (int j = 0; j < 8; ++j) st[j] = src[j * 256 + t];
#pragma unroll
        for (int j = 0; j < 8; ++j) ((float4*)xs)[j * 256 + t] = st[j];
        __syncthreads();
        // phase A: scores for this wave's 4 heads
#pragma unroll
        for (int r = 0; r < SUB_; ++r) {
            float4 xv[4];
#pragma unroll
            for (int k2 = 0; k2 < 4; ++k2) xv[k2] = *(const float4*)&xs[r * D_ + k2 * 256 + 4 * l];
            float p0 = 0.f, p1 = 0.f, p2 = 0.f, p3 = 0.f;
#pragma unroll
            for (int k2 = 0; k2 < 4; ++k2) {
                float4 x4 = xv[k2];
                p0 = fmaf(qkr[0][k2].x, x4.x, p0); p0 = fmaf(qkr[0][k2].y, x4.y, p0);
                p0 = fmaf(qkr[0][k2].z, x4.z, p0); p0 = fmaf(qkr[0][k2].w, x4.w, p0);
                p1 = fmaf(qkr[1][k2].x, x4.x, p1); p1 = fmaf(qkr[1][k2].y, x4.y, p1);
                p1 = fmaf(qkr[1][k2].z, x4.z, p1); p1 = fmaf(qkr[1][k2].w, x4.w, p1);
                p2 = fmaf(qkr[2][k2].x, x4.x, p2); p2 = fmaf(qkr[2][k2].y, x4.y, p2);
                p2 = fmaf(qkr[2][k2].z, x4.z, p2); p2 = fmaf(qkr[2][k2].w, x4.w, p2);
                p3 = fmaf(qkr[3][k2].x, x4.x, p3); p3 = fmaf(qkr[3][k2].y, x4.y, p3);
                p3 = fmaf(qkr[3][k2].z, x4.z, p3); p3 = fmaf(qkr[3][k2].w, x4.w, p3);
            }
#pragma unroll
            for (int o = 32; o > 0; o >>= 1) {
                p0 += __shfl_xor(p0, o); p1 += __shfl_xor(p1, o);
                p2 += __shfl_xor(p2, o); p3 += __shfl_xor(p3, o);
            }
            if (l == 0) {
                scs[w][r * 4 + 0] = (p0 + ckr[0]) * 0.125f;
                scs[w][r * 4 + 1] = (p1 + ckr[1]) * 0.125f;
                scs[w][r * 4 + 2] = (p2 + ckr[2]) * 0.125f;
                scs[w][r * 4 + 3] = (p3 + ckr[3]) * 0.125f;
            }
        }
        // phase C: online softmax update + weighted accumulate (wave-local scores)
        float mnew[4];
#pragma unroll
        for (int j = 0; j < 4; ++j) mnew[j] = mreg[j];
#pragma unroll
        for (int r = 0; r < SUB_; ++r)
#pragma unroll
            for (int j = 0; j < 4; ++j) mnew[j] = fmaxf(mnew[j], scs[w][r * 4 + j]);
#pragma unroll
        for (int j = 0; j < 4; ++j) {
            float f = __expf(mreg[j] - mnew[j]);
            lreg[j] *= f;
#pragma unroll
            for (int k2 = 0; k2 < 4; ++k2) {
                acc[j][k2].x *= f; acc[j][k2].y *= f; acc[j][k2].z *= f; acc[j][k2].w *= f;
            }
            mreg[j] = mnew[j];
        }
#pragma unroll
        for (int r = 0; r < SUB_; ++r) {
            float4 xv[4];
#pragma unroll
            for (int k2 = 0; k2 < 4; ++k2) xv[k2] = *(const float4*)&xs[r * D_ + k2 * 256 + 4 * l];
            float wg[4];
#pragma unroll
            for (int j = 0; j < 4; ++j) {
                wg[j] = __expf(scs[w][r * 4 + j] - mreg[j]);
                lreg[j] += wg[j];
            }
#pragma unroll
            for (int j = 0; j < 4; ++j)
#pragma unroll
                for (int k2 = 0; k2 < 4; ++k2) {
                    acc[j][k2].x = fmaf(wg[j], xv[k2].x, acc[j][k2].x);
                    acc[j][k2].y = fmaf(wg[j], xv[k2].y, acc[j][k2].y);
                    acc[j][k2].z = fmaf(wg[j], xv[k2].z, acc[j][k2].z);
                    acc[j][k2].w = fmaf(wg[j], xv[k2].w, acc[j][k2].w);
                }
        }
    }
    // write partials + m/l
#pragma unroll
    for (int j = 0; j < 4; ++j) {
        int h = w * 4 + j;
        size_t base = ((size_t)(c * B_ + b) * H_ + h) * D_;
#pragma unroll
        for (int k2 = 0; k2 < 4; ++k2)
            *(float4*)&part[base + k2 * 256 + 4 * l] = acc[j][k2];
        if (l == 0) {
            ml[(c * B_ + b) * H_ + h] = mreg[j];
            ml[ML_L_OFF + (c * B_ + b) * H_ + h] = lreg[j];
        }
    }
}

// ---------------- combine partials -> xctx ----------------
__global__ void k_combine(const float* __restrict__ part, const float* __restrict__ ml,
                          float* __restrict__ xctx) {
    int bh = blockIdx.x;   // b*H + h
    int t = threadIdx.x;
    __shared__ float mls[32];
    __shared__ float coef[16];
    if (t < 16) mls[t] = ml[t * (B_ * H_) + bh];
    else if (t < 32) mls[t] = ml[ML_L_OFF + (t - 16) * (B_ * H_) + bh];
    __syncthreads();
    if (t == 0) {
        float M = -1e30f;
        for (int c = 0; c < 16; ++c) M = fmaxf(M, mls[c]);
        float L = 0.f;
        for (int c = 0; c < 16; ++c) L += mls[16 + c] * __expf(mls[c] - M);
        float invL = 1.f / L;
        for (int c = 0; c < 16; ++c) coef[c] = __expf(mls[c] - M) * invL;
    }
    __syncthreads();
#pragma unroll
    for (int j = 0; j < 4; ++j) {
        int d = t + 256 * j;
        float a = 0.f;
#pragma unroll
        for (int c = 0; c < 16; ++c)
            a = fmaf(part[((size_t)(c * B_ * H_) + bh) * D_ + d], coef[c], a);
        xctx[(size_t)bh * D_ + d] = a;
    }
}

// ---------------- tail: ctx -> out_proj -> LN1 -> spectral -> denoise -> LN2 -> gate -> z3 ----
__global__ void k_tail(const float* __restrict__ ipw, const float* __restrict__ ipb,
                       const float* __restrict__ wout, const float* __restrict__ bout,
                       const float* __restrict__ zprev,
                       const float* __restrict__ ln1g, const float* __restrict__ ln1b,
                       const float* __restrict__ sreal, const float* __restrict__ simag,
                       const float* __restrict__ pw, const float* __restrict__ pb,
                       const float* __restrict__ ln2g, const float* __restrict__ ln2b,
                       const float* __restrict__ gate, const float* __restrict__ sattn,
                       const float* __restrict__ sden,
                       const float* __restrict__ xctx, float* __restrict__ z3out) {
    int b = blockIdx.x, t = threadIdx.x, w = t >> 6, l = t & 63;
    __shared__ float xc[H_ * D_];   // 64KB
    __shared__ float vec[D_];
    __shared__ float z1s[D_];
    __shared__ float zsps[D_];
    __shared__ float fre[16], fim[16], cre_[16], cim_[16];
    __shared__ float red_[8];
    for (int i = t; i < H_ * D_; i += 256) xc[i] = xctx[(size_t)b * (H_ * D_) + i];
    // filt
    {
        int m = t >> 4, sub = t & 15;
        float ar = 0.f, ai = 0.f;
        for (int k = sub; k < D_; k += 16) { ar += sreal[m * D_ + k]; ai += simag[m * D_ + k]; }
#pragma unroll
        for (int o = 8; o > 0; o >>= 1) { ar += __shfl_xor(ar, o, 16); ai += __shfl_xor(ai, o, 16); }
        if (sub == 0) { fre[m] = ar * (1.f / 1024.f); fim[m] = ai * (1.f / 1024.f); }
    }
    __syncthreads();
    // ctx GEMV (Wv)
    float ctxr[4];
#pragma unroll
    for (int j = 0; j < 4; ++j) {
        int n = t + 256 * j;
        int head = n >> 6;
        const float4* wr = (const float4*)(ipw + (size_t)(2 * D_ + n) * D_);
        const float4* xv4 = (const float4*)&xc[head * D_];
        float a = 0.f;
        for (int k = 0; k < 256; ++k) {
            float4 wv = wr[k], xv = xv4[k];
            a = fmaf(wv.x, xv.x, a); a = fmaf(wv.y, xv.y, a);
            a = fmaf(wv.z, xv.z, a); a = fmaf(wv.w, xv.w, a);
        }
        ctxr[j] = a + ipb[2 * D_ + n];
    }
#pragma unroll
    for (int j = 0; j < 4; ++j) vec[t + 256 * j] = ctxr[j];
    __syncthreads();
    // attn_out GEMV (Wo) + residual -> r1, LN1 stats
    float r1r[4];
    float s = 0.f, s2 = 0.f;
#pragma unroll
    for (int j = 0; j < 4; ++j) {
        int n = t + 256 * j;
        const float4* wr = (const float4*)(wout + (size_t)n * D_);
        const float4* xv4 = (const float4*)vec;
        float a = 0.f;
        for (int k = 0; k < 256; ++k) {
            float4 wv = wr[k], xv = xv4[k];
            a = fmaf(wv.x, xv.x, a); a = fmaf(wv.y, xv.y, a);
            a = fmaf(wv.z, xv.z, a); a = fmaf(wv.w, xv.w, a);
        }
        float v = zprev[(size_t)b * D_ + n] + sattn[0] * (a + bout[n]);
        r1r[j] = v; s += v; s2 = fmaf(v, v, s2);
    }
#pragma unroll
    for (int o = 32; o > 0; o >>= 1) { s += __shfl_xor(s, o); s2 += __shfl_xor(s2, o); }
    if (l == 0) { red_[w] = s; red_[4 + w] = s2; }
    __syncthreads();
    s = red_[0] + red_[1] + red_[2] + red_[3];
    s2 = red_[4] + red_[5] + red_[6] + red_[7];
    float mu = s * (1.f / 1024.f), var = s2 * (1.f / 1024.f) - mu * mu;
    float rs = rsqrtf(var + EPS_);
    float z1r[4];
#pragma unroll
    for (int j = 0; j < 4; ++j) {
        int n = t + 256 * j;
        float v = (r1r[j] - mu) * rs * ln1g[n] + ln1b[n];
        z1r[j] = v; z1s[n] = v;
    }
    __syncthreads();
    // spectral DFT (16 modes)
    {
        int m = t >> 4, sub = t & 15;
        const float step = 6.283185307179586f / 1024.f;
        float ar = 0.f, ai = 0.f;
        for (int k = sub; k < D_; k += 16) {
            int idx = (m * k) & 1023;
            float sn, cs; __sincosf(step * (float)idx, &sn, &cs);
            float z = z1s[k];
            ar = fmaf(z, cs, ar); ai = fmaf(-z, sn, ai);
        }
#pragma unroll
        for (int o = 8; o > 0; o >>= 1) { ar += __shfl_xor(ar, o, 16); ai += __shfl_xor(ai, o, 16); }
        if (sub == 0) {
            cre_[m] = (fre[m] * ar - fim[m] * ai) * (1.f / 1024.f);
            cim_[m] = (fre[m] * ai + fim[m] * ar) * (1.f / 1024.f);
        }
    }
    __syncthreads();
    // synthesize z_spatial
#pragma unroll
    for (int j = 0; j < 4; ++j) {
        int n = t + 256 * j;
        float a = 0.f;
        const float step = 6.283185307179586f / 1024.f;
#pragma unroll
        for (int mm = 0; mm < 16; ++mm) {
            int idx = (mm * n) & 1023;
            float sn, cs; __sincosf(step * (float)idx, &sn, &cs);
            a += cre_[mm] * cs - cim_[mm] * sn;
        }
        zsps[n] = a;
    }
    __syncthreads();
    // denoise GEMV (proj_w) + residual -> r2, LN2 stats
    float r2r[4]; s = 0.f; s2 = 0.f;
#pragma unroll
    for (int j = 0; j < 4; ++j) {
        int n = t + 256 * j;
        const float4* wr = (const float4*)(pw + (size_t)n * D_);
        const float4* xv4 = (const float4*)zsps;
        float a = 0.f;
        for (int k = 0; k < 256; ++k) {
            float4 wv = wr[k], xv = xv4[k];
            a = fmaf(wv.x, xv.x, a); a = fmaf(wv.y, xv.y, a);
            a = fmaf(wv.z, xv.z, a); a = fmaf(wv.w, xv.w, a);
        }
        float v = z1r[j] + sden[0] * (a + pb[n]);
        r2r[j] = v; s += v; s2 = fmaf(v, v, s2);
    }
#pragma unroll
    for (int o = 32; o > 0; o >>= 1) { s += __shfl_xor(s, o); s2 += __shfl_xor(s2, o); }
    if (l == 0) { red_[w] = s; red_[4 + w] = s2; }
    __syncthreads();
    s = red_[0] + red_[1] + red_[2] + red_[3];
    s2 = red_[4] + red_[5] + red_[6] + red_[7];
    mu = s * (1.f / 1024.f); var = s2 * (1.f / 1024.f) - mu * mu;
    rs = rsqrtf(var + EPS_);
    float gsig = 1.f / (1.f + __expf(-gate[0]));
#pragma unroll
    for (int j = 0; j < 4; ++j) {
        int n = t + 256 * j;
        float z2 = (r2r[j] - mu) * rs * ln2g[n] + ln2b[n];
        z3out[(size_t)b * D_ + n] = gsig * z2 + (1.f - gsig) * zprev[(size_t)b * D_ + n];
    }
}

// ---------------- batchnorm over B per column ----------------
__global__ void k_bn(const float* __restrict__ bng, const float* __restrict__ bnb,
                     const float* __restrict__ z3, float* __restrict__ out) {
    int d = blockIdx.x * 256 + threadIdx.x;
    float vals[B_];
    float s = 0.f, s2 = 0.f;
#pragma unroll
    for (int b = 0; b < B_; ++b) {
        float v = z3[(size_t)b * D_ + d];
        vals[b] = v; s += v; s2 = fmaf(v, v, s2);
    }
    float mu = s * (1.f / (float)B_);
    float var = s2 * (1.f / (float)B_) - mu * mu;
    float rs = rsqrtf(var + EPS_);
    float gg = bng[d], bb = bnb[d];
#pragma unroll
    for (int b = 0; b < B_; ++b) out[(size_t)b * D_ + d] = (vals[b] - mu) * rs * gg + bb;
}

extern "C" void kernel_launch(void* const* d_in, const int* in_sizes, int n_in,
                              void* d_out, int out_size, void* d_ws, size_t ws_size,
                              hipStream_t stream) {
    const float* x_feat = (const float*)d_in[0];
    const float* z_prev = (const float*)d_in[1];
    const float* ipw    = (const float*)d_in[2];
    const float* ipb    = (const float*)d_in[3];
    const float* wout   = (const float*)d_in[4];
    const float* bout   = (const float*)d_in[5];
    const float* ln1g   = (const float*)d_in[6];
    const float* ln1b   = (const float*)d_in[7];
    const float* ln2g   = (const float*)d_in[8];
    const float* ln2b   = (const float*)d_in[9];
    const float* sreal  = (const float*)d_in[10];
    const float* simag  = (const float*)d_in[11];
    const float* pw     = (const float*)d_in[12];
    const float* pb     = (const float*)d_in[13];
    const float* bng    = (const float*)d_in[14];
    const float* bnb    = (const float*)d_in[15];
    const float* gate   = (const float*)d_in[16];
    const float* sattn  = (const float*)d_in[17];
    const float* sden   = (const float*)d_in[18];
    float* ws  = (float*)d_ws;
    float* out = (float*)d_out;

    k_q<<<B_ * 4, 256, 0, stream>>>(z_prev, ipw, ipb, ws + OFF_Q, ws + OFF_CK);
    k_qkc<<<H_ * 16, 256, 0, stream>>>(ipw, ws + OFF_Q, ws + OFF_QK);
    k_attn<<<B_ * NCH_, 256, 0, stream>>>(x_feat, ws + OFF_QK, ws + OFF_CK,
                                          ws + OFF_PART, ws + OFF_ML);
    k_combine<<<B_ * H_, 256, 0, stream>>>(ws + OFF_PART, ws + OFF_ML, ws + OFF_XCTX);
    k_tail<<<B_, 256, 0, stream>>>(ipw, ipb, wout, bout, z_prev, ln1g, ln1b,
                                   sreal, simag, pw, pb, ln2g, ln2b, gate, sattn, sden,
                                   ws + OFF_XCTX, ws + OFF_Z3);
    k_bn<<<D_ / 256, 256, 0, stream>>>(bng, bnb, ws + OFF_Z3, out);
}

// Round 4
// 299.420 us; speedup vs baseline: 1.8824x; 1.8824x over previous
//
#include <hip/hip_runtime.h>
#include <math.h>

#define B_ 32
#define S_ 2048
#define D_ 1024
#define H_ 16
#define HD_ 64
#define MODES_ 16
#define EPS_ 1e-5f

#define CHUNK_ 128
#define SUB_ 8
#define NSUB_ (CHUNK_ / SUB_)   // 16
#define NCH_ (S_ / CHUNK_)      // 16 chunks

// workspace float offsets
#define OFF_FILT_RE 0
#define OFF_FILT_IM 16
#define OFF_CK      32            // B*H = 512
#define OFF_Q       1024          // B*D = 32768
#define OFF_QK      33792         // B*H*D = 524288
#define OFF_ML      558080        // 2 * NCH*B*H = 16384
#define ML_L_OFF    8192
#define OFF_PART    574464        // NCH*B*H*D = 8388608
#define OFF_XCTX    8963072       // B*H*D = 524288
#define OFF_CTX     9487360       // B*D
#define OFF_R1      9520128
#define OFF_Z1      9552896
#define OFF_ZSP     9585664
#define OFF_R2      9618432
#define OFF_Z3      9651200

// ---------------- filt[m] = mean_d(scale_real/imag[m,:]) ; one block per mode ----------------
__global__ void k_filt(const float* __restrict__ sr, const float* __restrict__ si, float* __restrict__ ws) {
    int m = blockIdx.x, t = threadIdx.x, w = t >> 6, l = t & 63;
    float4 a = ((const float4*)(sr + (size_t)m * D_))[t];
    float4 b = ((const float4*)(si + (size_t)m * D_))[t];
    float ar = a.x + a.y + a.z + a.w;
    float ai = b.x + b.y + b.z + b.w;
    __shared__ float sa[4], sb[4];
#pragma unroll
    for (int o = 32; o > 0; o >>= 1) { ar += __shfl_xor(ar, o); ai += __shfl_xor(ai, o); }
    if (l == 0) { sa[w] = ar; sb[w] = ai; }
    __syncthreads();
    if (t == 0) {
        ws[OFF_FILT_RE + m] = (sa[0] + sa[1] + sa[2] + sa[3]) * (1.f / (float)D_);
        ws[OFF_FILT_IM + m] = (sb[0] + sb[1] + sb[2] + sb[3]) * (1.f / (float)D_);
    }
}

// ---------------- q[b,n] = z_prev[b,:].Wq[n,:] + bq[n] ; ck[b,h] = q.bk ----------------
__global__ void k_q(const float* __restrict__ zprev, const float* __restrict__ ipw,
                    const float* __restrict__ ipb, float* __restrict__ q_out,
                    float* __restrict__ ck_out) {
    int b = blockIdx.x >> 2, nc = blockIdx.x & 3;
    __shared__ float zr[D_];
    int t = threadIdx.x;
    for (int i = t; i < D_; i += 256) zr[i] = zprev[(size_t)b * D_ + i];
    __syncthreads();
    int n = nc * 256 + t;
    const float4* wr = (const float4*)(ipw + (size_t)n * D_);
    float acc = 0.f;
    for (int k = 0; k < D_ / 4; ++k) {
        float4 wv = wr[k];
        float4 zv = *(const float4*)&zr[4 * k];
        acc = fmaf(zv.x, wv.x, acc); acc = fmaf(zv.y, wv.y, acc);
        acc = fmaf(zv.z, wv.z, acc); acc = fmaf(zv.w, wv.w, acc);
    }
    float qv = acc + ipb[n];
    q_out[(size_t)b * D_ + n] = qv;
    float cv = qv * ipb[D_ + n];
#pragma unroll
    for (int o = 32; o > 0; o >>= 1) cv += __shfl_xor(cv, o);
    if ((t & 63) == 0) ck_out[b * H_ + (n >> 6)] = cv;
}

// ---------------- qk[b,h,n] = sum_i q[b,h*64+i] * Wk[h*64+i, n] ----------------
__global__ void k_qkc(const float* __restrict__ ipw, const float* __restrict__ q_in,
                      float* __restrict__ qk_out) {
    int bid = blockIdx.x;
    int bc = bid & 3, nc = (bid >> 2) & 3, h = bid >> 4;
    int t = threadIdx.x;
    __shared__ float4 tile4[HD_ * 64];   // 64 rows x 256 cols = 64KB
    __shared__ float qall[8 * HD_];
    const float4* wk4 = (const float4*)(ipw + (size_t)D_ * D_);
#pragma unroll
    for (int j = 0; j < 16; ++j) {
        int lin4 = j * 256 + t;
        int i = lin4 >> 6, n4 = lin4 & 63;
        tile4[lin4] = wk4[(size_t)(h * HD_ + i) * 256 + nc * 64 + n4];
    }
#pragma unroll
    for (int j = 0; j < 2; ++j) {
        int idx = j * 256 + t;
        int bb = idx >> 6, i = idx & 63;
        qall[idx] = q_in[(size_t)(bc * 8 + bb) * D_ + h * HD_ + i];
    }
    __syncthreads();
    const float* tile = (const float*)tile4;
#pragma unroll
    for (int bb = 0; bb < 8; ++bb) {
        float acc = 0.f;
#pragma unroll
        for (int i = 0; i < HD_; ++i) acc = fmaf(qall[bb * HD_ + i], tile[i * 256 + t], acc);
        int b = bc * 8 + bb;
        qk_out[(size_t)(b * H_ + h) * D_ + nc * 256 + t] = acc;
    }
}

// ---------------- fused attention pass: online softmax partials over x_feat (single read) ----
__global__ __launch_bounds__(256, 2) void k_attn(const float* __restrict__ xfeat,
        const float* __restrict__ qk, const float* __restrict__ ck,
        float* __restrict__ part, float* __restrict__ ml) {
    int bid = blockIdx.x;
    int b = bid >> 4, c = bid & 15;
    int t = threadIdx.x, w = t >> 6, l = t & 63;
    __shared__ float xs[SUB_ * D_];      // 32KB
    __shared__ float scs[4][SUB_ * 4];   // per-wave scores
    float4 qkr[4][4];
    float ckr[4];
#pragma unroll
    for (int j = 0; j < 4; ++j) {
        int h = w * 4 + j;
        ckr[j] = ck[b * H_ + h];
#pragma unroll
        for (int k2 = 0; k2 < 4; ++k2)
            qkr[j][k2] = *(const float4*)(qk + (size_t)(b * H_ + h) * D_ + k2 * 256 + 4 * l);
    }
    float4 acc[4][4];
#pragma unroll
    for (int j = 0; j < 4; ++j)
#pragma unroll
        for (int k2 = 0; k2 < 4; ++k2) acc[j][k2] = make_float4(0.f, 0.f, 0.f, 0.f);
    float mreg[4] = {-1e30f, -1e30f, -1e30f, -1e30f};
    float lreg[4] = {0.f, 0.f, 0.f, 0.f};
    const float4* xbase = (const float4*)(xfeat + ((size_t)b * S_ + c * CHUNK_) * D_);
    for (int i = 0; i < NSUB_; ++i) {
        __syncthreads();
        const float4* src = xbase + (size_t)i * (SUB_ * D_ / 4);
        float4 st[8];
#pragma unroll
        for (int j = 0; j < 8; ++j) st[j] = src[j * 256 + t];
#pragma unroll
        for (int j = 0; j < 8; ++j) ((float4*)xs)[j * 256 + t] = st[j];
        __syncthreads();
        // phase A: scores for this wave's 4 heads
#pragma unroll
        for (int r = 0; r < SUB_; ++r) {
            float4 xv[4];
#pragma unroll
            for (int k2 = 0; k2 < 4; ++k2) xv[k2] = *(const float4*)&xs[r * D_ + k2 * 256 + 4 * l];
            float p0 = 0.f, p1 = 0.f, p2 = 0.f, p3 = 0.f;
#pragma unroll
            for (int k2 = 0; k2 < 4; ++k2) {
                float4 x4 = xv[k2];
                p0 = fmaf(qkr[0][k2].x, x4.x, p0); p0 = fmaf(qkr[0][k2].y, x4.y, p0);
                p0 = fmaf(qkr[0][k2].z, x4.z, p0); p0 = fmaf(qkr[0][k2].w, x4.w, p0);
                p1 = fmaf(qkr[1][k2].x, x4.x, p1); p1 = fmaf(qkr[1][k2].y, x4.y, p1);
                p1 = fmaf(qkr[1][k2].z, x4.z, p1); p1 = fmaf(qkr[1][k2].w, x4.w, p1);
                p2 = fmaf(qkr[2][k2].x, x4.x, p2); p2 = fmaf(qkr[2][k2].y, x4.y, p2);
                p2 = fmaf(qkr[2][k2].z, x4.z, p2); p2 = fmaf(qkr[2][k2].w, x4.w, p2);
                p3 = fmaf(qkr[3][k2].x, x4.x, p3); p3 = fmaf(qkr[3][k2].y, x4.y, p3);
                p3 = fmaf(qkr[3][k2].z, x4.z, p3); p3 = fmaf(qkr[3][k2].w, x4.w, p3);
            }
#pragma unroll
            for (int o = 32; o > 0; o >>= 1) {
                p0 += __shfl_xor(p0, o); p1 += __shfl_xor(p1, o);
                p2 += __shfl_xor(p2, o); p3 += __shfl_xor(p3, o);
            }
            if (l == 0) {
                scs[w][r * 4 + 0] = (p0 + ckr[0]) * 0.125f;
                scs[w][r * 4 + 1] = (p1 + ckr[1]) * 0.125f;
                scs[w][r * 4 + 2] = (p2 + ckr[2]) * 0.125f;
                scs[w][r * 4 + 3] = (p3 + ckr[3]) * 0.125f;
            }
        }
        // phase C: online softmax update + weighted accumulate (wave-local scores)
        float mnew[4];
#pragma unroll
        for (int j = 0; j < 4; ++j) mnew[j] = mreg[j];
#pragma unroll
        for (int r = 0; r < SUB_; ++r)
#pragma unroll
            for (int j = 0; j < 4; ++j) mnew[j] = fmaxf(mnew[j], scs[w][r * 4 + j]);
#pragma unroll
        for (int j = 0; j < 4; ++j) {
            float f = __expf(mreg[j] - mnew[j]);
            lreg[j] *= f;
#pragma unroll
            for (int k2 = 0; k2 < 4; ++k2) {
                acc[j][k2].x *= f; acc[j][k2].y *= f; acc[j][k2].z *= f; acc[j][k2].w *= f;
            }
            mreg[j] = mnew[j];
        }
#pragma unroll
        for (int r = 0; r < SUB_; ++r) {
            float4 xv[4];
#pragma unroll
            for (int k2 = 0; k2 < 4; ++k2) xv[k2] = *(const float4*)&xs[r * D_ + k2 * 256 + 4 * l];
            float wg[4];
#pragma unroll
            for (int j = 0; j < 4; ++j) {
                wg[j] = __expf(scs[w][r * 4 + j] - mreg[j]);
                lreg[j] += wg[j];
            }
#pragma unroll
            for (int j = 0; j < 4; ++j)
#pragma unroll
                for (int k2 = 0; k2 < 4; ++k2) {
                    acc[j][k2].x = fmaf(wg[j], xv[k2].x, acc[j][k2].x);
                    acc[j][k2].y = fmaf(wg[j], xv[k2].y, acc[j][k2].y);
                    acc[j][k2].z = fmaf(wg[j], xv[k2].z, acc[j][k2].z);
                    acc[j][k2].w = fmaf(wg[j], xv[k2].w, acc[j][k2].w);
                }
        }
    }
    // write partials + m/l
#pragma unroll
    for (int j = 0; j < 4; ++j) {
        int h = w * 4 + j;
        size_t base = ((size_t)(c * B_ + b) * H_ + h) * D_;
#pragma unroll
        for (int k2 = 0; k2 < 4; ++k2)
            *(float4*)&part[base + k2 * 256 + 4 * l] = acc[j][k2];
        if (l == 0) {
            ml[(c * B_ + b) * H_ + h] = mreg[j];
            ml[ML_L_OFF + (c * B_ + b) * H_ + h] = lreg[j];
        }
    }
}

// ---------------- combine partials -> xctx ----------------
__global__ void k_combine(const float* __restrict__ part, const float* __restrict__ ml,
                          float* __restrict__ xctx) {
    int bh = blockIdx.x;   // b*H + h
    int t = threadIdx.x;
    __shared__ float mls[32];
    __shared__ float coef[16];
    if (t < 16) mls[t] = ml[t * (B_ * H_) + bh];
    else if (t < 32) mls[t] = ml[ML_L_OFF + (t - 16) * (B_ * H_) + bh];
    __syncthreads();
    if (t == 0) {
        float M = -1e30f;
        for (int c = 0; c < 16; ++c) M = fmaxf(M, mls[c]);
        float L = 0.f;
        for (int c = 0; c < 16; ++c) L += mls[16 + c] * __expf(mls[c] - M);
        float invL = 1.f / L;
        for (int c = 0; c < 16; ++c) coef[c] = __expf(mls[c] - M) * invL;
    }
    __syncthreads();
#pragma unroll
    for (int j = 0; j < 4; ++j) {
        int d = t + 256 * j;
        float a = 0.f;
#pragma unroll
        for (int c = 0; c < 16; ++c)
            a = fmaf(part[((size_t)(c * B_ * H_) + bh) * D_ + d], coef[c], a);
        xctx[(size_t)bh * D_ + d] = a;
    }
}

// ---------------- ctx[b, n] = Wv[n,:] . xctx[b, n>>6, :] + bv[n] ----------------
__global__ void k_ctx(const float* __restrict__ ipw, const float* __restrict__ ipb,
                      const float* __restrict__ xctx, float* __restrict__ ctx) {
    int b = blockIdx.x >> 2, nc = blockIdx.x & 3;
    __shared__ float xr[4 * D_];   // 4 heads worth of xctx
    int t = threadIdx.x;
    for (int i = t; i < 4 * D_; i += 256)
        xr[i] = xctx[(size_t)(b * H_ + nc * 4) * D_ + i];
    __syncthreads();
    int n = nc * 256 + t;
    int hl = t >> 6;
    const float4* wr = (const float4*)(ipw + ((size_t)2 * D_ + n) * D_);
    const float4* xv4 = (const float4*)&xr[hl * D_];
    float acc = 0.f;
    for (int k = 0; k < D_ / 4; ++k) {
        float4 wv = wr[k], xv = xv4[k];
        acc = fmaf(wv.x, xv.x, acc); acc = fmaf(wv.y, xv.y, acc);
        acc = fmaf(wv.z, xv.z, acc); acc = fmaf(wv.w, xv.w, acc);
    }
    ctx[(size_t)b * D_ + n] = acc + ipb[2 * D_ + n];
}

// ---------------- out = resid + scale*(invec @ W.T + bias) ----------------
__global__ void k_proj_res(const float* __restrict__ wmat, const float* __restrict__ bias,
                           const float* __restrict__ scale, const float* __restrict__ resid,
                           const float* __restrict__ invec, float* __restrict__ outvec) {
    int b = blockIdx.x >> 2, nc = blockIdx.x & 3;
    __shared__ float cx[D_];
    int t = threadIdx.x;
    for (int i = t; i < D_; i += 256) cx[i] = invec[(size_t)b * D_ + i];
    __syncthreads();
    int n = nc * 256 + t;
    const float4* wr = (const float4*)(wmat + (size_t)n * D_);
    float acc = 0.f;
    for (int k = 0; k < D_ / 4; ++k) {
        float4 wv = wr[k];
        float4 cv = *(const float4*)&cx[4 * k];
        acc = fmaf(wv.x, cv.x, acc); acc = fmaf(wv.y, cv.y, acc);
        acc = fmaf(wv.z, cv.z, acc); acc = fmaf(wv.w, cv.w, acc);
    }
    outvec[(size_t)b * D_ + n] = resid[(size_t)b * D_ + n] + scale[0] * (acc + bias[n]);
}

// ---------------- layernorm over D (per b) ----------------
__global__ void k_ln(const float* __restrict__ inv, const float* __restrict__ g,
                     const float* __restrict__ bv, float* __restrict__ outv) {
    int b = blockIdx.x, t = threadIdx.x, w = t >> 6, l = t & 63;
    float4 v = ((const float4*)(inv + (size_t)b * D_))[t];
    float s = v.x + v.y + v.z + v.w;
    float s2 = v.x * v.x + v.y * v.y + v.z * v.z + v.w * v.w;
    __shared__ float sa[4], sb[4];
#pragma unroll
    for (int o = 32; o > 0; o >>= 1) { s += __shfl_xor(s, o); s2 += __shfl_xor(s2, o); }
    if (l == 0) { sa[w] = s; sb[w] = s2; }
    __syncthreads();
    s = sa[0] + sa[1] + sa[2] + sa[3];
    s2 = sb[0] + sb[1] + sb[2] + sb[3];
    float mu = s * (1.f / (float)D_);
    float var = s2 * (1.f / (float)D_) - mu * mu;
    float rs = rsqrtf(var + EPS_);
    float4 gg = ((const float4*)g)[t], bb = ((const float4*)bv)[t];
    float4 o4;
    o4.x = (v.x - mu) * rs * gg.x + bb.x;
    o4.y = (v.y - mu) * rs * gg.y + bb.y;
    o4.z = (v.z - mu) * rs * gg.z + bb.z;
    o4.w = (v.w - mu) * rs * gg.w + bb.w;
    ((float4*)(outv + (size_t)b * D_))[t] = o4;
}

// ---------------- spectral: 16-mode DFT of z1, filter, synthesize ----------------
__global__ void k_spec(float* __restrict__ ws) {
    int b = blockIdx.x, t = threadIdx.x;
    __shared__ float zr[D_];
    __shared__ float cre[MODES_], cim[MODES_];
    const float* z1 = ws + OFF_Z1 + (size_t)b * D_;
    for (int i = t; i < D_; i += 256) zr[i] = z1[i];
    __syncthreads();
    const float step = 6.283185307179586f / (float)D_;
    int m = t >> 4, sub = t & 15;
    float ar = 0.f, ai = 0.f;
    for (int n = sub; n < D_; n += 16) {
        int idx = (m * n) & (D_ - 1);
        float sn, cs;
        __sincosf(step * (float)idx, &sn, &cs);
        float z = zr[n];
        ar = fmaf(z, cs, ar); ai = fmaf(-z, sn, ai);
    }
#pragma unroll
    for (int o = 8; o > 0; o >>= 1) { ar += __shfl_xor(ar, o, 16); ai += __shfl_xor(ai, o, 16); }
    if (sub == 0) {
        float fr = ws[OFF_FILT_RE + m], fi = ws[OFF_FILT_IM + m];
        cre[m] = (fr * ar - fi * ai) * (1.f / (float)D_);
        cim[m] = (fr * ai + fi * ar) * (1.f / (float)D_);
    }
    __syncthreads();
    for (int n = t; n < D_; n += 256) {
        float acc = 0.f;
#pragma unroll
        for (int mm = 0; mm < MODES_; ++mm) {
            int idx = (mm * n) & (D_ - 1);
            float sn, cs;
            __sincosf(step * (float)idx, &sn, &cs);
            acc += cre[mm] * cs - cim[mm] * sn;
        }
        ws[OFF_ZSP + (size_t)b * D_ + n] = acc;
    }
}

// ---------------- LN2 + gate mix -> z3 ----------------
__global__ void k_ln2gate(const float* __restrict__ zprev, const float* __restrict__ g2,
                          const float* __restrict__ b2v, const float* __restrict__ gate,
                          float* __restrict__ ws) {
    int b = blockIdx.x, t = threadIdx.x, w = t >> 6, l = t & 63;
    float4 v = ((const float4*)(ws + OFF_R2 + (size_t)b * D_))[t];
    float s = v.x + v.y + v.z + v.w;
    float s2 = v.x * v.x + v.y * v.y + v.z * v.z + v.w * v.w;
    __shared__ float sa[4], sb[4];
#pragma unroll
    for (int o = 32; o > 0; o >>= 1) { s += __shfl_xor(s, o); s2 += __shfl_xor(s2, o); }
    if (l == 0) { sa[w] = s; sb[w] = s2; }
    __syncthreads();
    s = sa[0] + sa[1] + sa[2] + sa[3];
    s2 = sb[0] + sb[1] + sb[2] + sb[3];
    float mu = s * (1.f / (float)D_);
    float var = s2 * (1.f / (float)D_) - mu * mu;
    float rs = rsqrtf(var + EPS_);
    float4 gg = ((const float4*)g2)[t], bb = ((const float4*)b2v)[t];
    float gsig = 1.f / (1.f + __expf(-gate[0]));
    float4 zp = ((const float4*)(zprev + (size_t)b * D_))[t];
    float4 z3;
    z3.x = gsig * ((v.x - mu) * rs * gg.x + bb.x) + (1.f - gsig) * zp.x;
    z3.y = gsig * ((v.y - mu) * rs * gg.y + bb.y) + (1.f - gsig) * zp.y;
    z3.z = gsig * ((v.z - mu) * rs * gg.z + bb.z) + (1.f - gsig) * zp.z;
    z3.w = gsig * ((v.w - mu) * rs * gg.w + bb.w) + (1.f - gsig) * zp.w;
    ((float4*)(ws + OFF_Z3 + (size_t)b * D_))[t] = z3;
}

// ---------------- batchnorm over B per column ----------------
__global__ void k_bn(const float* __restrict__ bng, const float* __restrict__ bnb,
                     const float* __restrict__ z3, float* __restrict__ out) {
    int d = blockIdx.x * 256 + threadIdx.x;
    float vals[B_];
    float s = 0.f, s2 = 0.f;
#pragma unroll
    for (int b = 0; b < B_; ++b) {
        float v = z3[(size_t)b * D_ + d];
        vals[b] = v; s += v; s2 = fmaf(v, v, s2);
    }
    float mu = s * (1.f / (float)B_);
    float var = s2 * (1.f / (float)B_) - mu * mu;
    float rs = rsqrtf(var + EPS_);
    float gg = bng[d], bb = bnb[d];
#pragma unroll
    for (int b = 0; b < B_; ++b) out[(size_t)b * D_ + d] = (vals[b] - mu) * rs * gg + bb;
}

extern "C" void kernel_launch(void* const* d_in, const int* in_sizes, int n_in,
                              void* d_out, int out_size, void* d_ws, size_t ws_size,
                              hipStream_t stream) {
    const float* x_feat = (const float*)d_in[0];
    const float* z_prev = (const float*)d_in[1];
    const float* ipw    = (const float*)d_in[2];
    const float* ipb    = (const float*)d_in[3];
    const float* wout   = (const float*)d_in[4];
    const float* bout   = (const float*)d_in[5];
    const float* ln1g   = (const float*)d_in[6];
    const float* ln1b   = (const float*)d_in[7];
    const float* ln2g   = (const float*)d_in[8];
    const float* ln2b   = (const float*)d_in[9];
    const float* sreal  = (const float*)d_in[10];
    const float* simag  = (const float*)d_in[11];
    const float* pw     = (const float*)d_in[12];
    const float* pb     = (const float*)d_in[13];
    const float* bng    = (const float*)d_in[14];
    const float* bnb    = (const float*)d_in[15];
    const float* gate   = (const float*)d_in[16];
    const float* sattn  = (const float*)d_in[17];
    const float* sden   = (const float*)d_in[18];
    float* ws  = (float*)d_ws;
    float* out = (float*)d_out;

    k_filt<<<MODES_, 256, 0, stream>>>(sreal, simag, ws);
    k_q<<<B_ * 4, 256, 0, stream>>>(z_prev, ipw, ipb, ws + OFF_Q, ws + OFF_CK);
    k_qkc<<<H_ * 16, 256, 0, stream>>>(ipw, ws + OFF_Q, ws + OFF_QK);
    k_attn<<<B_ * NCH_, 256, 0, stream>>>(x_feat, ws + OFF_QK, ws + OFF_CK,
                                          ws + OFF_PART, ws + OFF_ML);
    k_combine<<<B_ * H_, 256, 0, stream>>>(ws + OFF_PART, ws + OFF_ML, ws + OFF_XCTX);
    k_ctx<<<B_ * 4, 256, 0, stream>>>(ipw, ipb, ws + OFF_XCTX, ws + OFF_CTX);
    k_proj_res<<<B_ * 4, 256, 0, stream>>>(wout, bout, sattn, z_prev, ws + OFF_CTX, ws + OFF_R1);
    k_ln<<<B_, 256, 0, stream>>>(ws + OFF_R1, ln1g, ln1b, ws + OFF_Z1);
    k_spec<<<B_, 256, 0, stream>>>(ws);
    k_proj_res<<<B_ * 4, 256, 0, stream>>>(pw, pb, sden, ws + OFF_Z1, ws + OFF_ZSP, ws + OFF_R2);
    k_ln2gate<<<B_, 256, 0, stream>>>(z_prev, ln2g, ln2b, gate, ws);
    k_bn<<<D_ / 256, 256, 0, stream>>>(bng, bnb, ws + OFF_Z3, out);
}